// Round 1
// baseline (599.467 us; speedup 1.0000x reference)
//
#include <hip/hip_runtime.h>

#define F_DIM 128
#define UNROLL 8

__device__ __forceinline__ void flush_acc(float* dst, const float4& a) {
    atomicAdd(dst + 0, a.x);
    atomicAdd(dst + 1, a.y);
    atomicAdd(dst + 2, a.z);
    atomicAdd(dst + 3, a.w);
}

// One 32-lane half-wave owns a contiguous chunk of rows. Lane j holds float4
// of features [4j..4j+3]. Processes 8 rows per batch: all loads issued before
// any use (8x MLP), 8 independent butterfly-reduce chains (DS latency
// overlapped), flush branch amortized per batch.
__global__ __launch_bounds__(256) void fused_gate_segsum(
    const float* __restrict__ atom_feats, const float* __restrict__ vir_feats,
    const float* __restrict__ W_atom, const float* __restrict__ b_atom,
    const float* __restrict__ W_vir, const float* __restrict__ b_vir,
    const int* __restrict__ atom_seg, const int* __restrict__ vir_seg,
    float* __restrict__ out_atom, float* __restrict__ out_vir,
    float* __restrict__ logits,
    int n_atom, int n_vir, int g_atom, int rpg_atom, int rpg_vir)
{
    const int group = (int)((blockIdx.x * blockDim.x + threadIdx.x) >> 5);
    const int lane  = threadIdx.x & 31;

    const float* feats; const float* W; const float* bp; const int* seg;
    float* out; float* lg; int n_rows; int row_start; int rpg;
    if (group < g_atom) {
        feats = atom_feats; W = W_atom; bp = b_atom; seg = atom_seg;
        out = out_atom; lg = logits; n_rows = n_atom; rpg = rpg_atom;
        row_start = group * rpg;
    } else {
        const int g = group - g_atom;
        feats = vir_feats; W = W_vir; bp = b_vir; seg = vir_seg;
        out = out_vir; lg = nullptr; n_rows = n_vir; rpg = rpg_vir;
        row_start = g * rpg;
    }
    if (row_start >= n_rows) return;
    int row_end = row_start + rpg;
    if (row_end > n_rows) row_end = n_rows;

    const float4 w4 = ((const float4*)W)[lane];
    const float bias = *bp;

    float4 acc = make_float4(0.f, 0.f, 0.f, 0.f);
    int cur = seg[row_start];
    float mylog = 0.f;   // logit of row (window_base + lane) in current 32-row window

    int r = row_start;
    // row_start is rpg-aligned; rpg in {64,16} is a multiple of 8, and
    // n_atom/n_vir divide evenly, so this main loop covers everything.
    for (; r + UNROLL <= row_end; r += UNROLL) {
        // ---- batched loads: all issued before any use ----
        float4 v[UNROLL];
        #pragma unroll
        for (int j = 0; j < UNROLL; ++j)
            v[j] = ((const float4*)(feats + (size_t)(r + j) * F_DIM))[lane];
        const int4 sa = *(const int4*)(seg + r);
        const int4 sb = *(const int4*)(seg + r + 4);
        const int s[UNROLL] = {sa.x, sa.y, sa.z, sa.w, sb.x, sb.y, sb.z, sb.w};

        // ---- 8 partial dots ----
        float d[UNROLL];
        #pragma unroll
        for (int j = 0; j < UNROLL; ++j)
            d[j] = v[j].x * w4.x + v[j].y * w4.y + v[j].z * w4.z + v[j].w * w4.w;

        // ---- 8 interleaved butterfly chains (independent -> latency overlap) ----
        #pragma unroll
        for (int m = 16; m >= 1; m >>= 1) {
            #pragma unroll
            for (int j = 0; j < UNROLL; ++j)
                d[j] += __shfl_xor(d[j], m, 32);
        }

        // ---- logits + sigmoid weights ----
        #pragma unroll
        for (int j = 0; j < UNROLL; ++j) {
            const float logit = d[j] + bias;
            if (lg) {
                if (lane == ((r + j) & 31)) mylog = logit;
            }
            d[j] = 1.0f / (1.0f + __expf(-logit));   // reuse d[] as weight
        }
        // store one full 32-row window every 4th batch (r+8 is 32-aligned then)
        if (lg && (((r + UNROLL - 1) & 31) == 31)) {
            lg[(r + UNROLL - 32) + lane] = mylog;    // coalesced 128B store
        }

        // ---- accumulate, rare flush on segment change ----
        #pragma unroll
        for (int j = 0; j < UNROLL; ++j) {
            if (s[j] != cur) {
                flush_acc(out + (size_t)cur * F_DIM + lane * 4, acc);
                acc = make_float4(0.f, 0.f, 0.f, 0.f);
                cur = s[j];
            }
            acc.x += d[j] * v[j].x; acc.y += d[j] * v[j].y;
            acc.z += d[j] * v[j].z; acc.w += d[j] * v[j].w;
        }
    }

    // ---- scalar tail (cold with current sizes) ----
    for (; r < row_end; ++r) {
        const int sv = seg[r];
        const float4 v = ((const float4*)(feats + (size_t)r * F_DIM))[lane];
        float dot = v.x * w4.x + v.y * w4.y + v.z * w4.z + v.w * w4.w;
        #pragma unroll
        for (int m = 16; m >= 1; m >>= 1) dot += __shfl_xor(dot, m, 32);
        const float logit = dot + bias;
        if (lg) {
            if (lane == (r & 31)) mylog = logit;
            if ((r & 31) == 31) lg[r - 31 + lane] = mylog;
        }
        const float wgt = 1.0f / (1.0f + __expf(-logit));
        if (sv != cur) {
            flush_acc(out + (size_t)cur * F_DIM + lane * 4, acc);
            acc = make_float4(0.f, 0.f, 0.f, 0.f);
            cur = sv;
        }
        acc.x += wgt * v.x; acc.y += wgt * v.y;
        acc.z += wgt * v.z; acc.w += wgt * v.w;
    }
    flush_acc(out + (size_t)cur * F_DIM + lane * 4, acc);

    // logits tail (rows past the last aligned 32-window; cold with current sizes)
    if (lg) {
        const int rem = row_end & 31;
        if (rem && lane < rem) {
            lg[(row_end & ~31) + lane] = mylog;
        }
    }
}

extern "C" void kernel_launch(void* const* d_in, const int* in_sizes, int n_in,
                              void* d_out, int out_size, void* d_ws, size_t ws_size,
                              hipStream_t stream) {
    const float* atom_feats = (const float*)d_in[0];
    const float* vir_feats  = (const float*)d_in[1];
    const float* W_atom     = (const float*)d_in[2];
    const float* b_atom     = (const float*)d_in[3];
    const float* W_vir      = (const float*)d_in[4];
    const float* b_vir      = (const float*)d_in[5];
    const int*   atom_seg   = (const int*)d_in[6];
    const int*   vir_seg    = (const int*)d_in[7];

    const int n_atom = in_sizes[0] / F_DIM;
    const int n_vir  = in_sizes[1] / F_DIM;
    const int num_graphs = (out_size - n_atom) / (2 * F_DIM);

    float* out_atom = (float*)d_out;
    float* out_vir  = out_atom + (size_t)num_graphs * F_DIM;
    float* logits   = out_vir  + (size_t)num_graphs * F_DIM;

    // zero the two segment-sum regions (harness poisons d_out with 0xAA)
    hipMemsetAsync(d_out, 0, (size_t)2 * num_graphs * F_DIM * sizeof(float), stream);

    const int RPG_ATOM = 64;   // avg segment ~50 rows -> ~2 flushes/chunk
    const int RPG_VIR  = 16;   // avg segment ~4 rows  -> ~5 flushes/chunk
    const int g_atom = (n_atom + RPG_ATOM - 1) / RPG_ATOM;
    const int g_vir  = (n_vir  + RPG_VIR  - 1) / RPG_VIR;
    const int total_groups = g_atom + g_vir;
    const int block = 256;                      // 8 half-wave groups per block
    const int grid = (total_groups * 32 + block - 1) / block;

    fused_gate_segsum<<<grid, block, 0, stream>>>(
        atom_feats, vir_feats, W_atom, b_atom, W_vir, b_vir,
        atom_seg, vir_seg, out_atom, out_vir, logits,
        n_atom, n_vir, g_atom, RPG_ATOM, RPG_VIR);
}

// Round 13
// 579.544 us; speedup vs baseline: 1.0344x; 1.0344x over previous
//
#include <hip/hip_runtime.h>

#define F_DIM 128

// clang vector type accepted by __builtin_nontemporal_load (HIP's float4 is a
// class and is rejected).
typedef float fvec4 __attribute__((ext_vector_type(4)));

__device__ __forceinline__ void flush_acc(float* dst, const float4& a) {
    atomicAdd(dst + 0, a.x);
    atomicAdd(dst + 1, a.y);
    atomicAdd(dst + 2, a.z);
    atomicAdd(dst + 3, a.w);
}

__device__ __forceinline__ float4 nt_load4(const float* p) {
    fvec4 t = __builtin_nontemporal_load((const fvec4*)p);
    return make_float4(t.x, t.y, t.z, t.w);
}

// 4-row batch held entirely in named registers (rule: no runtime-indexed arrays).
struct Batch {
    float4 v0, v1, v2, v3;
    int4 s;
};

__device__ __forceinline__ void load_batch(Batch& b, const float* __restrict__ feats,
                                           const int* __restrict__ seg, int r, int lane) {
    // lane L holds features [4L..4L+3] of each row; rows are 512B apart.
    const float* p = feats + (size_t)r * F_DIM + lane * 4;
    b.v0 = nt_load4(p);
    b.v1 = nt_load4(p + F_DIM);
    b.v2 = nt_load4(p + 2 * F_DIM);
    b.v3 = nt_load4(p + 3 * F_DIM);
    b.s  = *(const int4*)(seg + r);
}

__device__ __forceinline__ float sigmoid_fast(float x) {
    return __builtin_amdgcn_rcpf(1.0f + __expf(-x));
}

__device__ __forceinline__ void compute_batch(
    const Batch& b, const float4& w4, float bias, int r, int lane,
    float4& acc, int& cur, float& mylog,
    float* __restrict__ out, float* __restrict__ lg)
{
    // 4 partial dots
    float d0 = b.v0.x * w4.x + b.v0.y * w4.y + b.v0.z * w4.z + b.v0.w * w4.w;
    float d1 = b.v1.x * w4.x + b.v1.y * w4.y + b.v1.z * w4.z + b.v1.w * w4.w;
    float d2 = b.v2.x * w4.x + b.v2.y * w4.y + b.v2.z * w4.z + b.v2.w * w4.w;
    float d3 = b.v3.x * w4.x + b.v3.y * w4.y + b.v3.z * w4.z + b.v3.w * w4.w;

    // 4 interleaved butterfly chains (independent -> DS latency overlap)
    #pragma unroll
    for (int m = 16; m >= 1; m >>= 1) {
        d0 += __shfl_xor(d0, m, 32);
        d1 += __shfl_xor(d1, m, 32);
        d2 += __shfl_xor(d2, m, 32);
        d3 += __shfl_xor(d3, m, 32);
    }

    const float l0 = d0 + bias;
    const float l1 = d1 + bias;
    const float l2 = d2 + bias;
    const float l3 = d3 + bias;

    if (lg) {   // uniform per group
        if (lane == ((r + 0) & 31)) mylog = l0;
        if (lane == ((r + 1) & 31)) mylog = l1;
        if (lane == ((r + 2) & 31)) mylog = l2;
        if (lane == ((r + 3) & 31)) mylog = l3;
        if (((r + 3) & 31) == 31) lg[r + 3 - 31 + lane] = mylog;  // coalesced 128B
    }

    const float g0 = sigmoid_fast(l0);
    const float g1 = sigmoid_fast(l1);
    const float g2 = sigmoid_fast(l2);
    const float g3 = sigmoid_fast(l3);

    // accumulate; flush on (rare) segment change
    if (b.s.x != cur) {
        flush_acc(out + (size_t)cur * F_DIM + lane * 4, acc);
        acc = make_float4(0.f, 0.f, 0.f, 0.f);
        cur = b.s.x;
    }
    acc.x += g0 * b.v0.x; acc.y += g0 * b.v0.y; acc.z += g0 * b.v0.z; acc.w += g0 * b.v0.w;
    if (b.s.y != cur) {
        flush_acc(out + (size_t)cur * F_DIM + lane * 4, acc);
        acc = make_float4(0.f, 0.f, 0.f, 0.f);
        cur = b.s.y;
    }
    acc.x += g1 * b.v1.x; acc.y += g1 * b.v1.y; acc.z += g1 * b.v1.z; acc.w += g1 * b.v1.w;
    if (b.s.z != cur) {
        flush_acc(out + (size_t)cur * F_DIM + lane * 4, acc);
        acc = make_float4(0.f, 0.f, 0.f, 0.f);
        cur = b.s.z;
    }
    acc.x += g2 * b.v2.x; acc.y += g2 * b.v2.y; acc.z += g2 * b.v2.z; acc.w += g2 * b.v2.w;
    if (b.s.w != cur) {
        flush_acc(out + (size_t)cur * F_DIM + lane * 4, acc);
        acc = make_float4(0.f, 0.f, 0.f, 0.f);
        cur = b.s.w;
    }
    acc.x += g3 * b.v3.x; acc.y += g3 * b.v3.y; acc.z += g3 * b.v3.z; acc.w += g3 * b.v3.w;
}

__global__ __launch_bounds__(256) void fused_gate_segsum(
    const float* __restrict__ atom_feats, const float* __restrict__ vir_feats,
    const float* __restrict__ W_atom, const float* __restrict__ b_atom,
    const float* __restrict__ W_vir, const float* __restrict__ b_vir,
    const int* __restrict__ atom_seg, const int* __restrict__ vir_seg,
    float* __restrict__ out_atom, float* __restrict__ out_vir,
    float* __restrict__ logits,
    int n_atom, int n_vir, int g_atom, int rpg_atom, int rpg_vir)
{
    const int group = (int)((blockIdx.x * blockDim.x + threadIdx.x) >> 5);
    const int lane  = threadIdx.x & 31;

    const float* feats; const float* W; const float* bp; const int* seg;
    float* out; float* lg; int n_rows; int row_start; int rpg;
    if (group < g_atom) {
        feats = atom_feats; W = W_atom; bp = b_atom; seg = atom_seg;
        out = out_atom; lg = logits; n_rows = n_atom; rpg = rpg_atom;
        row_start = group * rpg;
    } else {
        const int g = group - g_atom;
        feats = vir_feats; W = W_vir; bp = b_vir; seg = vir_seg;
        out = out_vir; lg = nullptr; n_rows = n_vir; rpg = rpg_vir;
        row_start = g * rpg;
    }
    if (row_start >= n_rows) return;
    int row_end = row_start + rpg;
    if (row_end > n_rows) row_end = n_rows;

    const float4 w4 = ((const float4*)W)[lane];
    const float bias = *bp;

    float4 acc = make_float4(0.f, 0.f, 0.f, 0.f);
    int cur = seg[row_start];
    float mylog = 0.f;   // logit of row (window_base + lane) in current 32-row window

    // ---- 2-stage software pipeline over 4-row batches ----
    int r = row_start;
    const int nfull = (row_end - row_start) >> 2;   // # of full 4-row batches
    Batch A, B;
    if (nfull > 0) load_batch(A, feats, seg, r, lane);
    int bidx = 0;
    for (; bidx + 2 <= nfull; bidx += 2) {
        load_batch(B, feats, seg, r + 4, lane);                   // prefetch k+1
        compute_batch(A, w4, bias, r, lane, acc, cur, mylog, out, lg);
        if (bidx + 2 < nfull)
            load_batch(A, feats, seg, r + 8, lane);               // prefetch k+2
        compute_batch(B, w4, bias, r + 4, lane, acc, cur, mylog, out, lg);
        r += 8;
    }
    if (bidx < nfull) {   // odd leftover batch (A already loaded)
        compute_batch(A, w4, bias, r, lane, acc, cur, mylog, out, lg);
        r += 4;
    }

    // ---- scalar tail (cold with current sizes) ----
    for (; r < row_end; ++r) {
        const int sv = seg[r];
        const float4 v = ((const float4*)(feats + (size_t)r * F_DIM))[lane];
        float dot = v.x * w4.x + v.y * w4.y + v.z * w4.z + v.w * w4.w;
        #pragma unroll
        for (int m = 16; m >= 1; m >>= 1) dot += __shfl_xor(dot, m, 32);
        const float logit = dot + bias;
        if (lg) {
            if (lane == (r & 31)) mylog = logit;
            if ((r & 31) == 31) lg[r - 31 + lane] = mylog;
        }
        const float wgt = sigmoid_fast(logit);
        if (sv != cur) {
            flush_acc(out + (size_t)cur * F_DIM + lane * 4, acc);
            acc = make_float4(0.f, 0.f, 0.f, 0.f);
            cur = sv;
        }
        acc.x += wgt * v.x; acc.y += wgt * v.y;
        acc.z += wgt * v.z; acc.w += wgt * v.w;
    }
    flush_acc(out + (size_t)cur * F_DIM + lane * 4, acc);

    // logits tail (rows past the last aligned 32-window; cold with current sizes)
    if (lg) {
        const int rem = row_end & 31;
        if (rem && lane < rem) {
            lg[(row_end & ~31) + lane] = mylog;
        }
    }
}

extern "C" void kernel_launch(void* const* d_in, const int* in_sizes, int n_in,
                              void* d_out, int out_size, void* d_ws, size_t ws_size,
                              hipStream_t stream) {
    const float* atom_feats = (const float*)d_in[0];
    const float* vir_feats  = (const float*)d_in[1];
    const float* W_atom     = (const float*)d_in[2];
    const float* b_atom     = (const float*)d_in[3];
    const float* W_vir      = (const float*)d_in[4];
    const float* b_vir      = (const float*)d_in[5];
    const int*   atom_seg   = (const int*)d_in[6];
    const int*   vir_seg    = (const int*)d_in[7];

    const int n_atom = in_sizes[0] / F_DIM;
    const int n_vir  = in_sizes[1] / F_DIM;
    const int num_graphs = (out_size - n_atom) / (2 * F_DIM);

    float* out_atom = (float*)d_out;
    float* out_vir  = out_atom + (size_t)num_graphs * F_DIM;
    float* logits   = out_vir  + (size_t)num_graphs * F_DIM;

    // zero the two segment-sum regions (harness poisons d_out with 0xAA)
    (void)hipMemsetAsync(d_out, 0, (size_t)2 * num_graphs * F_DIM * sizeof(float), stream);

    const int RPG_ATOM = 128;  // avg segment ~50 rows -> ~3 flushes/chunk; 6400 streams
    const int RPG_VIR  = 32;   // avg segment ~4 rows  -> ~9 flushes/chunk; 2048 streams
    const int g_atom = (n_atom + RPG_ATOM - 1) / RPG_ATOM;
    const int g_vir  = (n_vir  + RPG_VIR  - 1) / RPG_VIR;
    const int total_groups = g_atom + g_vir;
    const int block = 256;                      // 8 half-wave groups per block
    const int grid = (total_groups * 32 + block - 1) / block;

    fused_gate_segsum<<<grid, block, 0, stream>>>(
        atom_feats, vir_feats, W_atom, b_atom, W_vir, b_vir,
        atom_seg, vir_seg, out_atom, out_vir, logits,
        n_atom, n_vir, g_atom, RPG_ATOM, RPG_VIR);
}